// Round 2
// baseline (95.064 us; speedup 1.0000x reference)
//
#include <hip/hip_runtime.h>
#include <hip/hip_bf16.h>
#include <stdint.h>

typedef __attribute__((ext_vector_type(4))) int   i32x4;
typedef __attribute__((ext_vector_type(8))) int   i32x8;
typedef __attribute__((ext_vector_type(4))) float f32x4;

#define MDIM   4096
#define NDIM   4096
#define KBYTES 2048   // K=4096 fp4 elems -> 2048 packed bytes per row
#define NKBLK  128    // K/32 scale blocks per row

#define BM   128
#define BN   128
#define BKB  128                 // K-bytes per step (= 256 fp4 elems = 8 scale blocks)
#define KSTEPS (KBYTES / BKB)    // 16

// ---------------- repack: int32-per-byte -> packed bytes ----------------
__global__ void repack_bytes(const int* __restrict__ a, const int* __restrict__ b,
                             uint32_t* __restrict__ ap, uint32_t* __restrict__ bp) {
  const size_t n4 = (size_t)MDIM * KBYTES / 4;  // 2M output dwords per matrix
  for (size_t i = (size_t)blockIdx.x * blockDim.x + threadIdx.x; i < n4;
       i += (size_t)gridDim.x * blockDim.x) {
    i32x4 va = *(const i32x4*)(a + i * 4);
    ap[i] = (uint32_t)(va.x & 255) | ((uint32_t)(va.y & 255) << 8) |
            ((uint32_t)(va.z & 255) << 16) | ((uint32_t)(va.w & 255) << 24);
    i32x4 vb = *(const i32x4*)(b + i * 4);
    bp[i] = (uint32_t)(vb.x & 255) | ((uint32_t)(vb.y & 255) << 8) |
            ((uint32_t)(vb.z & 255) << 16) | ((uint32_t)(vb.w & 255) << 24);
  }
}

// -------- scales: float biased-exp -> uint8 E8M0, layout [kb][m&15][m>>4] ------
// A lane needing rows {ms*16 + l15 : ms=0..3} at fixed kb reads ONE dword:
//   satX[kb*4096 + l15*256 + (rowbase>>4)]  -> bytes = scales for ms=0..3
__global__ void repack_scales(const float* __restrict__ sa, const float* __restrict__ sb,
                              uint8_t* __restrict__ sat, uint8_t* __restrict__ sbt) {
  int t = blockIdx.x * blockDim.x + threadIdx.x;
  if (t >= MDIM * NKBLK) return;
  int m  = t >> 7;     // row
  int kb = t & 127;    // k-block
  int o  = kb * 4096 + (m & 15) * 256 + (m >> 4);
  sat[o] = (uint8_t)(int)sa[t];
  sbt[o] = (uint8_t)(int)sb[t];
}

__device__ __forceinline__ i32x8 frag8(i32x4 v) {
  i32x8 r = {v.x, v.y, v.z, v.w, 0, 0, 0, 0};
  return r;
}

// ---------------- MXFP4 GEMM: C[m][n] = sum_k A[m,k]*B[n,k] ----------------
__global__ __launch_bounds__(256) void mxfp4_gemm(
    const uint8_t* __restrict__ ap, const uint8_t* __restrict__ bp,
    const uint8_t* __restrict__ sat, const uint8_t* __restrict__ sbt,
    float* __restrict__ out) {
  __shared__ __align__(16) uint8_t lA[BM * BKB];  // 16 KB, xor-swizzled slots
  __shared__ __align__(16) uint8_t lB[BN * BKB];  // 16 KB

  const int tid  = threadIdx.x;
  const int lane = tid & 63;
  const int w    = tid >> 6;        // wave 0..3
  const int wrow = w >> 1;          // 2x2 wave grid, each wave does 64x64
  const int wcol = w & 1;
  const int g    = lane >> 4;       // k-group 0..3 (32 fp4 elems each)
  const int l15  = lane & 15;
  const int lx   = lane & 7;        // read-side xor term (== row&7 for our rows)

  const int bx = blockIdx.x;        // n tile
  const int by = blockIdx.y;        // m tile

  const uint8_t* aBase = ap + (size_t)(by * BM) * KBYTES;
  const uint8_t* bBase = bp + (size_t)(bx * BN) * KBYTES;

  // staging: each global_load_lds writes 1KB = 8 rows x 128B, linear LDS dest.
  // source slot is pre-swizzled so LDS[row][s] holds global slot s^(row&7).
  const int srow  = lane >> 3;              // 0..7 within the 8-row group
  const int sslot = (lane & 7) ^ srow;      // involution
  const int soff  = srow * KBYTES + sslot * 16;

  // per-lane scale dword pointers: step ks, half kw -> +(ks*8+kw*4)*4096
  const uint8_t* sAp = sat + (size_t)g * 4096 + l15 * 256 + by * 8 + wrow * 4;
  const uint8_t* sBp = sbt + (size_t)g * 4096 + l15 * 256 + bx * 8 + wcol * 4;

  f32x4 acc[4][4] = {};

  for (int ks = 0; ks < KSTEPS; ++ks) {
    const int k0 = ks * BKB;
#pragma unroll
    for (int q = 0; q < 4; ++q) {
      const int r0 = (w * 4 + q) * 8;       // first row of this 1KB chunk
      __builtin_amdgcn_global_load_lds(
          (__attribute__((address_space(1))) void*)(aBase + (size_t)r0 * KBYTES + k0 + soff),
          (__attribute__((address_space(3))) void*)(lA + (w * 4 + q) * 1024),
          16, 0, 0);
      __builtin_amdgcn_global_load_lds(
          (__attribute__((address_space(1))) void*)(bBase + (size_t)r0 * KBYTES + k0 + soff),
          (__attribute__((address_space(3))) void*)(lB + (w * 4 + q) * 1024),
          16, 0, 0);
    }
    // prefetch this step's scale dwords (latency hides under the vmcnt(0)
    // drain of the staging loads at the barrier)
    const uint32_t sa0 = *(const uint32_t*)(sAp + (size_t)(ks * 8 + 0) * 4096);
    const uint32_t sa1 = *(const uint32_t*)(sAp + (size_t)(ks * 8 + 4) * 4096);
    const uint32_t sb0 = *(const uint32_t*)(sBp + (size_t)(ks * 8 + 0) * 4096);
    const uint32_t sb1 = *(const uint32_t*)(sBp + (size_t)(ks * 8 + 4) * 4096);

    __syncthreads();   // drains vmcnt -> staging + scale loads complete

#pragma unroll
    for (int kw = 0; kw < 2; ++kw) {        // two K=128 mfma chunks per step
      const uint32_t saK = kw ? sa1 : sa0;
      const uint32_t sbK = kw ? sb1 : sb0;
      const int slotx = ((kw * 4 + g) ^ lx) * 16;
      i32x4 af[4], bf[4];
#pragma unroll
      for (int ms = 0; ms < 4; ++ms) {
        const int row = wrow * 64 + ms * 16 + l15;
        af[ms] = *(const i32x4*)(lA + row * BKB + slotx);
      }
#pragma unroll
      for (int ns = 0; ns < 4; ++ns) {
        const int row = wcol * 64 + ns * 16 + l15;
        bf[ns] = *(const i32x4*)(lB + row * BKB + slotx);
      }
#pragma unroll
      for (int ms = 0; ms < 4; ++ms) {
        const int sA = (saK >> (ms * 8)) & 0xff;
#pragma unroll
        for (int ns = 0; ns < 4; ++ns) {
          const int sB = (sbK >> (ns * 8)) & 0xff;
          acc[ms][ns] = __builtin_amdgcn_mfma_scale_f32_16x16x128_f8f6f4(
              frag8(af[ms]), frag8(bf[ns]), acc[ms][ns],
              4 /*cbsz: FP4*/, 4 /*blgp: FP4*/,
              0, sA, 0, sB);
        }
      }
    }
    __syncthreads();   // all reads done before next staging overwrites LDS
  }

  // epilogue: D lane mapping (16x16 shapes): row=(lane>>4)*4+r, col=lane&15
  float* ob = out + (size_t)(by * BM + wrow * 64) * NDIM + bx * BN + wcol * 64;
#pragma unroll
  for (int ms = 0; ms < 4; ++ms)
#pragma unroll
    for (int ns = 0; ns < 4; ++ns) {
#pragma unroll
      for (int r = 0; r < 4; ++r)
        ob[(size_t)(ms * 16 + g * 4 + r) * NDIM + ns * 16 + l15] = acc[ms][ns][r];
    }
}

extern "C" void kernel_launch(void* const* d_in, const int* in_sizes, int n_in,
                              void* d_out, int out_size, void* d_ws, size_t ws_size,
                              hipStream_t stream) {
  (void)in_sizes; (void)n_in; (void)out_size; (void)ws_size;
  const int*   a  = (const int*)d_in[0];
  const int*   b  = (const int*)d_in[1];
  const float* sa = (const float*)d_in[2];
  const float* sb = (const float*)d_in[3];
  float* out = (float*)d_out;

  uint8_t* ws = (uint8_t*)d_ws;
  uint32_t* ap = (uint32_t*)ws;                          // 8 MB packed A
  uint32_t* bp = (uint32_t*)(ws + (8u << 20));           // 8 MB packed B
  uint8_t*  sat = ws + (16u << 20);                      // 512 KB scales A (transposed)
  uint8_t*  sbt = ws + (16u << 20) + (512u << 10);       // 512 KB scales B (transposed)

  repack_bytes<<<2048, 256, 0, stream>>>(a, b, ap, bp);
  repack_scales<<<(MDIM * NKBLK + 255) / 256, 256, 0, stream>>>(sa, sb, sat, sbt);

  dim3 grid(NDIM / BN, MDIM / BM);
  mxfp4_gemm<<<grid, 256, 0, stream>>>((const uint8_t*)ap, (const uint8_t*)bp,
                                       sat, sbt, out);
}

// Round 4
// 79.913 us; speedup vs baseline: 1.1896x; 1.1896x over previous
//
#include <hip/hip_runtime.h>
#include <hip/hip_bf16.h>
#include <stdint.h>

typedef __attribute__((ext_vector_type(4))) int   i32x4;
typedef __attribute__((ext_vector_type(8))) int   i32x8;
typedef __attribute__((ext_vector_type(4))) float f32x4;
typedef __attribute__((ext_vector_type(2))) unsigned int u32x2;

#define MDIM   4096
#define NDIM   4096
#define KBYTES 2048   // K=4096 fp4 elems -> 2048 packed bytes per row
#define NKBLK  128    // K/32 scale blocks per row

#define BM   256
#define BN   256
#define BKB  128                 // K-bytes per tile step (= 256 fp4 elems = 8 scale blocks)
#define KT   (KBYTES / BKB)      // 16 K-tiles

// Fence-carrying barrier: s_barrier alone is NOT a compiler memory fence;
// the "memory" clobber stops hipcc hoisting ds_reads / global_load_lds across
// it (the round-3 race: next-phase ds_reads hoisted above the tile-end
// barrier, reading LDS before OTHER waves' staging drained).
#define BARF()  asm volatile("s_barrier" ::: "memory")
#define LGKM0() asm volatile("s_waitcnt lgkmcnt(0)" ::: "memory")
#define VM0()   asm volatile("s_waitcnt vmcnt(0)" ::: "memory")

// ---------------- repack: int32-per-byte -> packed bytes ----------------
__global__ void repack_bytes(const int* __restrict__ a, const int* __restrict__ b,
                             uint32_t* __restrict__ ap, uint32_t* __restrict__ bp) {
  const size_t n4 = (size_t)MDIM * KBYTES / 4;
  for (size_t i = (size_t)blockIdx.x * blockDim.x + threadIdx.x; i < n4;
       i += (size_t)gridDim.x * blockDim.x) {
    i32x4 va = *(const i32x4*)(a + i * 4);
    ap[i] = (uint32_t)(va.x & 255) | ((uint32_t)(va.y & 255) << 8) |
            ((uint32_t)(va.z & 255) << 16) | ((uint32_t)(va.w & 255) << 24);
    i32x4 vb = *(const i32x4*)(b + i * 4);
    bp[i] = (uint32_t)(vb.x & 255) | ((uint32_t)(vb.y & 255) << 8) |
            ((uint32_t)(vb.z & 255) << 16) | ((uint32_t)(vb.w & 255) << 24);
  }
}

// -------- scales: float biased-exp -> uint8 E8M0, layout [kb][m&15][m>>4] ------
__global__ void repack_scales(const float* __restrict__ sa, const float* __restrict__ sb,
                              uint8_t* __restrict__ sat, uint8_t* __restrict__ sbt) {
  int t = blockIdx.x * blockDim.x + threadIdx.x;
  if (t >= MDIM * NKBLK) return;
  int m  = t >> 7;     // row
  int kb = t & 127;    // k-block
  int o  = kb * 4096 + (m & 15) * 256 + (m >> 4);
  sat[o] = (uint8_t)(int)sa[t];
  sbt[o] = (uint8_t)(int)sb[t];
}

__device__ __forceinline__ i32x8 frag8(i32x4 v) {
  i32x8 r = {v.x, v.y, v.z, v.w, 0, 0, 0, 0};
  return r;
}

__device__ __forceinline__ int sbyte2(u32x2 p, int i) {
  return (int)((i < 4 ? (p.x >> (i * 8)) : (p.y >> ((i - 4) * 8))) & 0xffu);
}

// ---------------- MXFP4 GEMM, 256x256 tile, 8 waves, 8-phase-style schedule ----
__global__ __launch_bounds__(512, 2) void mxfp4_gemm(
    const uint8_t* __restrict__ ap, const uint8_t* __restrict__ bp,
    const uint8_t* __restrict__ sat, const uint8_t* __restrict__ sbt,
    float* __restrict__ out) {
  extern __shared__ uint8_t lds[];   // 128 KB: [buf][A 32K | B 32K]

  const int tid  = threadIdx.x;
  const int lane = tid & 63;
  const int w    = tid >> 6;        // wave 0..7
  const int wrow = w >> 2;          // 2 M-waves
  const int wcol = w & 3;           // 4 N-waves
  const int g    = lane >> 4;       // k-group 0..3
  const int l15  = lane & 15;
  const int lx   = l15 & 7;         // read-side xor (== row&7 for frag rows)

  const int bx = blockIdx.x;
  const int by = blockIdx.y;

  const uint8_t* aBase = ap + (size_t)(by * BM) * KBYTES;
  const uint8_t* bBase = bp + (size_t)(bx * BN) * KBYTES;

  // staging source swizzle: LDS slot d holds global slot d^(row&7)
  const int srow  = lane >> 3;
  const int sslot = (lane & 7) ^ srow;
  const int soff  = srow * KBYTES + sslot * 16;
  const int arow0 = w * 32;         // each wave stages 32 A-rows and 32 B-rows

  // scale pointers (layout [kb][m&15][m>>4])
  const uint8_t* sAp = sat + (size_t)l15 * 256 + by * 16 + wrow * 8;
  const uint8_t* sBp = sbt + (size_t)l15 * 256 + bx * 16 + wcol * 4;

#define STAGE_A(dstbase, kt1, c)                                                         \
  __builtin_amdgcn_global_load_lds(                                                      \
      (__attribute__((address_space(1))) void*)(aBase + (size_t)(arow0 + (c) * 8) * KBYTES + (kt1) * BKB + soff), \
      (__attribute__((address_space(3))) void*)((dstbase) + (arow0 + (c) * 8) * 128), 16, 0, 0)
#define STAGE_B(dstbase, kt1, c)                                                         \
  __builtin_amdgcn_global_load_lds(                                                      \
      (__attribute__((address_space(1))) void*)(bBase + (size_t)(arow0 + (c) * 8) * KBYTES + (kt1) * BKB + soff), \
      (__attribute__((address_space(3))) void*)((dstbase) + 32768 + (arow0 + (c) * 8) * 128), 16, 0, 0)

  f32x4 acc[8][4] = {};
  i32x4 a0[4], a1[4], bf[4];
  u32x2 sAc0, sAc1, sAn0, sAn1;
  uint32_t sBc0, sBc1, sBn0, sBn1;

  // ---------------- prologue: stage tile 0 into buf0, load tile-0 scales ----------
  {
    uint8_t* d = lds;
#pragma unroll
    for (int c = 0; c < 4; ++c) { STAGE_A(d, 0, c); STAGE_B(d, 0, c); }
    sAc0 = *(const u32x2*)(sAp + (size_t)(0 + g) * 4096);
    sAc1 = *(const u32x2*)(sAp + (size_t)(4 + g) * 4096);
    sBc0 = *(const uint32_t*)(sBp + (size_t)(0 + g) * 4096);
    sBc1 = *(const uint32_t*)(sBp + (size_t)(4 + g) * 4096);
    VM0();
    BARF();
  }

  for (int kt = 0; kt < KT; ++kt) {
    const int cur = kt & 1;
    uint8_t* cA = lds + cur * 65536;
    uint8_t* cB = cA + 32768;
    uint8_t* nD = lds + (cur ^ 1) * 65536;
    const bool pf = (kt + 1 < KT);

    // ================= P0: bf(kw0), a0..3(kw0); prefetch A of kt+1 =================
#pragma unroll
    for (int ns = 0; ns < 4; ++ns)
      bf[ns] = *(const i32x4*)(cB + (wcol * 64 + ns * 16 + l15) * 128 + ((0 + g) ^ lx) * 16);
#pragma unroll
    for (int ms = 0; ms < 4; ++ms)
      a0[ms] = *(const i32x4*)(cA + (wrow * 128 + ms * 16 + l15) * 128 + ((0 + g) ^ lx) * 16);
    if (pf) {
#pragma unroll
      for (int c = 0; c < 4; ++c) STAGE_A(nD, kt + 1, c);
    }
    BARF();
    LGKM0();
    __builtin_amdgcn_s_setprio(1);
#pragma unroll
    for (int ms = 0; ms < 4; ++ms) {
      const int sa = sbyte2(sAc0, ms);
#pragma unroll
      for (int ns = 0; ns < 4; ++ns)
        acc[ms][ns] = __builtin_amdgcn_mfma_scale_f32_16x16x128_f8f6f4(
            frag8(a0[ms]), frag8(bf[ns]), acc[ms][ns], 4, 4,
            0, sa, 0, (int)((sBc0 >> (ns * 8)) & 0xffu));
    }
    __builtin_amdgcn_s_setprio(0);
    BARF();

    // ================= P1: a4..7(kw0); prefetch B of kt+1; next scales ============
#pragma unroll
    for (int ms = 0; ms < 4; ++ms)
      a1[ms] = *(const i32x4*)(cA + (wrow * 128 + (ms + 4) * 16 + l15) * 128 + ((0 + g) ^ lx) * 16);
    if (pf) {
#pragma unroll
      for (int c = 0; c < 4; ++c) STAGE_B(nD, kt + 1, c);
      sAn0 = *(const u32x2*)(sAp + (size_t)((kt + 1) * 8 + 0 + g) * 4096);
      sAn1 = *(const u32x2*)(sAp + (size_t)((kt + 1) * 8 + 4 + g) * 4096);
      sBn0 = *(const uint32_t*)(sBp + (size_t)((kt + 1) * 8 + 0 + g) * 4096);
      sBn1 = *(const uint32_t*)(sBp + (size_t)((kt + 1) * 8 + 4 + g) * 4096);
    }
    BARF();
    LGKM0();
    __builtin_amdgcn_s_setprio(1);
#pragma unroll
    for (int ms = 0; ms < 4; ++ms) {
      const int sa = sbyte2(sAc0, ms + 4);
#pragma unroll
      for (int ns = 0; ns < 4; ++ns)
        acc[ms + 4][ns] = __builtin_amdgcn_mfma_scale_f32_16x16x128_f8f6f4(
            frag8(a1[ms]), frag8(bf[ns]), acc[ms + 4][ns], 4, 4,
            0, sa, 0, (int)((sBc0 >> (ns * 8)) & 0xffu));
    }
    __builtin_amdgcn_s_setprio(0);
    BARF();

    // ================= P2: bf(kw1), a0..3(kw1) ====================================
#pragma unroll
    for (int ns = 0; ns < 4; ++ns)
      bf[ns] = *(const i32x4*)(cB + (wcol * 64 + ns * 16 + l15) * 128 + ((4 + g) ^ lx) * 16);
#pragma unroll
    for (int ms = 0; ms < 4; ++ms)
      a0[ms] = *(const i32x4*)(cA + (wrow * 128 + ms * 16 + l15) * 128 + ((4 + g) ^ lx) * 16);
    BARF();
    LGKM0();
    __builtin_amdgcn_s_setprio(1);
#pragma unroll
    for (int ms = 0; ms < 4; ++ms) {
      const int sa = sbyte2(sAc1, ms);
#pragma unroll
      for (int ns = 0; ns < 4; ++ns)
        acc[ms][ns] = __builtin_amdgcn_mfma_scale_f32_16x16x128_f8f6f4(
            frag8(a0[ms]), frag8(bf[ns]), acc[ms][ns], 4, 4,
            0, sa, 0, (int)((sBc1 >> (ns * 8)) & 0xffu));
    }
    __builtin_amdgcn_s_setprio(0);
    BARF();

    // ================= P3: a4..7(kw1); drain prefetch; tile-end barrier ===========
#pragma unroll
    for (int ms = 0; ms < 4; ++ms)
      a1[ms] = *(const i32x4*)(cA + (wrow * 128 + (ms + 4) * 16 + l15) * 128 + ((4 + g) ^ lx) * 16);
    BARF();
    LGKM0();
    __builtin_amdgcn_s_setprio(1);
#pragma unroll
    for (int ms = 0; ms < 4; ++ms) {
      const int sa = sbyte2(sAc1, ms + 4);
#pragma unroll
      for (int ns = 0; ns < 4; ++ns)
        acc[ms + 4][ns] = __builtin_amdgcn_mfma_scale_f32_16x16x128_f8f6f4(
            frag8(a1[ms]), frag8(bf[ns]), acc[ms + 4][ns], 4, 4,
            0, sa, 0, (int)((sBc1 >> (ns * 8)) & 0xffu));
    }
    __builtin_amdgcn_s_setprio(0);
    // rotate scales for next tile
    sAc0 = sAn0; sAc1 = sAn1; sBc0 = sBn0; sBc1 = sBn1;
    // drain own staging (issued >=2 phases ago, ~free), then fence-barrier:
    // after this barrier ALL waves' stages for kt+1 have landed.
    VM0();
    BARF();
  }

  // epilogue: D mapping row=(lane>>4)*4+r, col=lane&15 per 16x16 block
  float* ob = out + (size_t)(by * BM + wrow * 128) * NDIM + bx * BN + wcol * 64;
#pragma unroll
  for (int ms = 0; ms < 8; ++ms)
#pragma unroll
    for (int ns = 0; ns < 4; ++ns) {
#pragma unroll
      for (int r = 0; r < 4; ++r)
        ob[(size_t)(ms * 16 + g * 4 + r) * NDIM + ns * 16 + l15] = acc[ms][ns][r];
    }
#undef STAGE_A
#undef STAGE_B
}

extern "C" void kernel_launch(void* const* d_in, const int* in_sizes, int n_in,
                              void* d_out, int out_size, void* d_ws, size_t ws_size,
                              hipStream_t stream) {
  (void)in_sizes; (void)n_in; (void)out_size; (void)ws_size;
  const int*   a  = (const int*)d_in[0];
  const int*   b  = (const int*)d_in[1];
  const float* sa = (const float*)d_in[2];
  const float* sb = (const float*)d_in[3];
  float* out = (float*)d_out;

  uint8_t* ws = (uint8_t*)d_ws;
  uint32_t* ap = (uint32_t*)ws;                          // 8 MB packed A
  uint32_t* bp = (uint32_t*)(ws + (8u << 20));           // 8 MB packed B
  uint8_t*  sat = ws + (16u << 20);                      // 512 KB scales A
  uint8_t*  sbt = ws + (16u << 20) + (512u << 10);       // 512 KB scales B

  repack_bytes<<<2048, 256, 0, stream>>>(a, b, ap, bp);
  repack_scales<<<(MDIM * NKBLK + 255) / 256, 256, 0, stream>>>(sa, sb, sat, sbt);

  // 128 KB dynamic LDS needs the opt-in attribute (process-level, idempotent)
  hipFuncSetAttribute((const void*)mxfp4_gemm,
                      hipFuncAttributeMaxDynamicSharedMemorySize, 131072);

  dim3 grid(NDIM / BN, MDIM / BM);   // 16 x 16 = 256 blocks = 1/CU
  mxfp4_gemm<<<grid, 512, 131072, stream>>>((const uint8_t*)ap, (const uint8_t*)bp,
                                            sat, sbt, out);
}